// Round 1
// baseline (55.788 us; speedup 1.0000x reference)
//
#include <hip/hip_runtime.h>

#define NN 512
#define DD 128
#define HH 256
#define OO 256
#define TI 4
#define JCH 128
#define JS 4

__global__ __launch_bounds__(256) void k_papb(const float* __restrict__ x,
                                              const float* __restrict__ W1,
                                              float* __restrict__ pa,
                                              float* __restrict__ pb) {
    __shared__ float xs[TI][DD];
    const int j0 = blockIdx.x * TI;
    const int t = threadIdx.x;
    {
        int idx = t;
        xs[idx >> 7][idx & 127] = x[j0 * DD + idx];
        idx = t + 256;
        xs[idx >> 7][idx & 127] = x[j0 * DD + idx];
    }
    __syncthreads();
    const int h = t;
    float accA[TI] = {0.f, 0.f, 0.f, 0.f};
    float accB[TI] = {0.f, 0.f, 0.f, 0.f};
    const float4* wa = (const float4*)(W1 + h * (2 * DD));
    const float4* wb = (const float4*)(W1 + h * (2 * DD) + DD);
    #pragma unroll 4
    for (int d4 = 0; d4 < DD / 4; ++d4) {
        float4 a = wa[d4];
        float4 b = wb[d4];
        #pragma unroll
        for (int ti = 0; ti < TI; ++ti) {
            float4 xv = *(const float4*)&xs[ti][d4 * 4];
            accA[ti] += a.x * xv.x + a.y * xv.y + a.z * xv.z + a.w * xv.w;
            accB[ti] += b.x * xv.x + b.y * xv.y + b.z * xv.z + b.w * xv.w;
        }
    }
    #pragma unroll
    for (int ti = 0; ti < TI; ++ti) {
        pa[(j0 + ti) * HH + h] = accA[ti];
        pb[(j0 + ti) * HH + h] = accB[ti];
    }
}

__global__ __launch_bounds__(64) void k_rowsum(const float* __restrict__ adj,
                                               float* __restrict__ rs) {
    const int i = blockIdx.x;
    const int lane = threadIdx.x;
    const float* row = adj + i * NN;
    float s = 0.f;
    #pragma unroll
    for (int j = 0; j < NN / 64; ++j) s += row[lane + j * 64];
    #pragma unroll
    for (int off = 32; off > 0; off >>= 1) s += __shfl_down(s, off, 64);
    if (lane == 0) rs[i] = s;
}

__global__ __launch_bounds__(256) void k_T(const float* __restrict__ pa,
                                           const float* __restrict__ pb,
                                           const float* __restrict__ b1,
                                           const float* __restrict__ adj,
                                           float* __restrict__ Tpart) {
    __shared__ float adj_s[TI * JCH];
    const int jc = blockIdx.x;             // 0..JS-1
    const int i0 = blockIdx.y * TI;
    const int t = threadIdx.x;
    {
        int idx = t;
        adj_s[idx] = adj[(i0 + (idx >> 7)) * NN + jc * JCH + (idx & 127)];
        idx = t + 256;
        adj_s[idx] = adj[(i0 + (idx >> 7)) * NN + jc * JCH + (idx & 127)];
    }
    const int h = t;
    const float bb = b1[h];
    float pbh[TI];
    float acc[TI] = {0.f, 0.f, 0.f, 0.f};
    #pragma unroll
    for (int ti = 0; ti < TI; ++ti) pbh[ti] = pb[(i0 + ti) * HH + h] + bb;
    __syncthreads();
    const float* pac = pa + (jc * JCH) * HH + h;
    for (int jj = 0; jj < JCH; jj += 4) {
        float p0 = pac[(jj + 0) * HH];
        float p1 = pac[(jj + 1) * HH];
        float p2 = pac[(jj + 2) * HH];
        float p3 = pac[(jj + 3) * HH];
        #pragma unroll
        for (int ti = 0; ti < TI; ++ti) {
            float4 a = *(const float4*)&adj_s[ti * JCH + jj];
            acc[ti] += a.x * fmaxf(p0 + pbh[ti], 0.f);
            acc[ti] += a.y * fmaxf(p1 + pbh[ti], 0.f);
            acc[ti] += a.z * fmaxf(p2 + pbh[ti], 0.f);
            acc[ti] += a.w * fmaxf(p3 + pbh[ti], 0.f);
        }
    }
    float* Tp = Tpart + jc * (NN * HH);
    #pragma unroll
    for (int ti = 0; ti < TI; ++ti) Tp[(i0 + ti) * HH + h] = acc[ti];
}

__global__ __launch_bounds__(256) void k_out(const float* __restrict__ Tpart,
                                             const float* __restrict__ rs,
                                             const float* __restrict__ W2,
                                             const float* __restrict__ b2,
                                             const float* __restrict__ Wo1,
                                             const float* __restrict__ bo1,
                                             const float* __restrict__ Wo2,
                                             const float* __restrict__ bo2,
                                             float* __restrict__ out) {
    __shared__ float bufA[TI][HH];
    __shared__ float bufB[TI][HH];
    const int i0 = blockIdx.x * TI;
    const int t = threadIdx.x;
    #pragma unroll
    for (int ti = 0; ti < TI; ++ti) {
        float s = 0.f;
        #pragma unroll
        for (int jc = 0; jc < JS; ++jc)
            s += Tpart[jc * (NN * HH) + (i0 + ti) * HH + t];
        bufA[ti][t] = s;
    }
    float rsv[TI];
    #pragma unroll
    for (int ti = 0; ti < TI; ++ti) rsv[ti] = rs[i0 + ti];
    __syncthreads();
    const int k = t;
    // stage 1: pred -> bufB
    {
        float acc[TI] = {0.f, 0.f, 0.f, 0.f};
        const float4* w = (const float4*)(W2 + k * HH);
        #pragma unroll 4
        for (int h4 = 0; h4 < HH / 4; ++h4) {
            float4 wv = w[h4];
            #pragma unroll
            for (int ti = 0; ti < TI; ++ti) {
                float4 xv = *(const float4*)&bufA[ti][h4 * 4];
                acc[ti] += wv.x * xv.x + wv.y * xv.y + wv.z * xv.z + wv.w * xv.w;
            }
        }
        const float bk = b2[k];
        #pragma unroll
        for (int ti = 0; ti < TI; ++ti)
            bufB[ti][k] = (acc[ti] + bk * rsv[ti]) * (1.0f / (float)NN);
    }
    __syncthreads();
    // stage 2: h2 = relu(pred @ Wo1.T + bo1) -> bufA
    {
        float acc[TI] = {0.f, 0.f, 0.f, 0.f};
        const float4* w = (const float4*)(Wo1 + k * HH);
        #pragma unroll 4
        for (int h4 = 0; h4 < HH / 4; ++h4) {
            float4 wv = w[h4];
            #pragma unroll
            for (int ti = 0; ti < TI; ++ti) {
                float4 xv = *(const float4*)&bufB[ti][h4 * 4];
                acc[ti] += wv.x * xv.x + wv.y * xv.y + wv.z * xv.z + wv.w * xv.w;
            }
        }
        const float bk = bo1[k];
        #pragma unroll
        for (int ti = 0; ti < TI; ++ti)
            bufA[ti][k] = fmaxf(acc[ti] + bk, 0.f);
    }
    __syncthreads();
    // stage 3: out = h2 @ Wo2.T + bo2
    {
        float acc[TI] = {0.f, 0.f, 0.f, 0.f};
        const float4* w = (const float4*)(Wo2 + k * HH);
        #pragma unroll 4
        for (int h4 = 0; h4 < HH / 4; ++h4) {
            float4 wv = w[h4];
            #pragma unroll
            for (int ti = 0; ti < TI; ++ti) {
                float4 xv = *(const float4*)&bufA[ti][h4 * 4];
                acc[ti] += wv.x * xv.x + wv.y * xv.y + wv.z * xv.z + wv.w * xv.w;
            }
        }
        const float bk = bo2[k];
        #pragma unroll
        for (int ti = 0; ti < TI; ++ti)
            out[(i0 + ti) * OO + k] = acc[ti] + bk;
    }
}

extern "C" void kernel_launch(void* const* d_in, const int* in_sizes, int n_in,
                              void* d_out, int out_size, void* d_ws, size_t ws_size,
                              hipStream_t stream) {
    const float* x   = (const float*)d_in[0];
    const float* adj = (const float*)d_in[1];
    const float* W1  = (const float*)d_in[2];
    const float* b1  = (const float*)d_in[3];
    const float* W2  = (const float*)d_in[4];
    const float* b2  = (const float*)d_in[5];
    const float* Wo1 = (const float*)d_in[6];
    const float* bo1 = (const float*)d_in[7];
    const float* Wo2 = (const float*)d_in[8];
    const float* bo2 = (const float*)d_in[9];
    float* out = (float*)d_out;

    float* ws = (float*)d_ws;
    float* pa    = ws;                   // 512*256
    float* pb    = ws + 131072;          // 512*256
    float* rsum  = ws + 262144;          // 512
    float* Tpart = ws + 262656;          // 4 * 512*256

    k_papb<<<NN / TI, 256, 0, stream>>>(x, W1, pa, pb);
    k_rowsum<<<NN, 64, 0, stream>>>(adj, rsum);
    k_T<<<dim3(JS, NN / TI), 256, 0, stream>>>(pa, pb, b1, adj, Tpart);
    k_out<<<NN / TI, 256, 0, stream>>>(Tpart, rsum, W2, b2, Wo1, bo1, Wo2, bo2, out);
}